// Round 1
// 2609.319 us; speedup vs baseline: 2.5114x; 2.5114x over previous
//
#include <hip/hip_runtime.h>
#include <hip/hip_bf16.h>

// SimpleLSTM on MI355X — round 4: latency-chain attack.
//   B=64, S=512, I=512, H=1024, gates = 4H = 4096
// R3 post-mortem: 12.7us/step with all pipes <3% busy -> pure cross-CU latency.
// R4 changes (same 4-group x 64-CU decomposition, same math):
//   1. Wave = K-slice (not gate x K-half): each wave loads a DISTINCT h chunk.
//      Coherent LLC h-traffic drops 128KB -> 32KB per CU per step (4x).
//   2. 8 arrival counters per group (atomicAdd, 8 CUs/line) instead of 64
//      per-CU flags: poll is an 8-line gather, 8x less LLC poll pressure.
//   3. x-part GEMM pipelined AFTER publish (hides under flag propagation);
//      publish directly from elementwise threads (shfl pair-pack -> 4B
//      coherent stores), no htile LDS round trip.

#define BATCH 64
#define SEQ   512
#define ISZ   512
#define HSZ   1024
#define G4    4096

typedef short bf16x8 __attribute__((ext_vector_type(8)));
typedef float f32x4  __attribute__((ext_vector_type(4)));

#define HEX_BYTES (2 * BATCH * HSZ * 2)     // 2 buffers x [64][1024] bf16 = 256 KB
#define FLAG_STRIDE_DW 32                   // 128 B between counters
#define FLAG_BYTES (4 * 64 * FLAG_STRIDE_DW * 4)

static __device__ __forceinline__ short f2bf(float f) {
    __hip_bfloat16 h = __float2bfloat16(f);
    return *reinterpret_cast<short*>(&h);
}
static __device__ __forceinline__ float sigm(float x) {
    return 1.f / (1.f + __expf(-x));
}
static __device__ __forceinline__ float tanh_fast(float x) {
    x = fminf(15.f, fmaxf(-15.f, x));
    float e = __expf(2.f * x);
    return (e - 1.f) / (e + 1.f);
}

__global__ __launch_bounds__(512) void lstm_persistent(
    const float* __restrict__ x,     // [B][S][I] fp32
    const float* __restrict__ W,     // [I+H][4H] fp32
    const float* __restrict__ bias,  // [4H] fp32
    float* __restrict__ out,         // [B][S][H] outputs, then [B][H] h, [B][H] c
    unsigned short* __restrict__ hex,// [2][B][H] bf16 exchange (coherent atomics only)
    unsigned int* __restrict__ flags)// per-group arrival counters, 128 B stride
{
    const int tid  = threadIdx.x;
    const int bid  = blockIdx.x;
    const int q    = bid & 63;          // CU index within group (owns cols q*16..+16 of each gate)
    const int g    = bid >> 6;          // batch group 0..3
    const int w    = tid >> 6;          // wave 0..7 = K-slice owner
    const int lane = tid & 63;
    const int m16  = lane & 15;
    const int quad = lane >> 4;
    const int batch0 = g * 16;

    // ---- preload weights as MFMA B-fragments ----
    // wave w covers h-K [w*128, w*128+128) and x-K [w*64, w*64+64), all 4 gates.
    // B-frag layout (16x16x32 bf16): lane holds B[k = quad*8 + j][n = lane&15]
    bf16x8 wh[4][4];   // [gate][kk]: Wh[w*128 + kk*32 ..][gate*1024 + q*16 ..+16]
    bf16x8 wx[4][2];   // [gate][kk]: Wx[w*64  + kk*32 ..][gate*1024 + q*16 ..+16]
    {
        #pragma unroll
        for (int gg = 0; gg < 4; ++gg) {
            const int colbase = gg * 1024 + q * 16 + m16;
            #pragma unroll
            for (int kk = 0; kk < 4; ++kk)
                #pragma unroll
                for (int j = 0; j < 8; ++j) {
                    int k = w * 128 + kk * 32 + quad * 8 + j;
                    wh[gg][kk][j] = f2bf(W[(size_t)(ISZ + k) * G4 + colbase]);
                }
            #pragma unroll
            for (int kk = 0; kk < 2; ++kk)
                #pragma unroll
                for (int j = 0; j < 8; ++j) {
                    int k = w * 64 + kk * 32 + quad * 8 + j;
                    wx[gg][kk][j] = f2bf(W[(size_t)k * G4 + colbase]);
                }
        }
    }

    // elementwise mapping (tid < 256): em = batch-in-group, en = col-in-16
    const int em = tid >> 4;
    const int en = tid & 15;
    float bia[4];
    #pragma unroll
    for (int gg = 0; gg < 4; ++gg) bia[gg] = bias[gg * 1024 + q * 16 + en];

    float c_state = 0.f;

    // 8 waves x 4 gates x 16x16 partials; stride 20 -> 2-way bank alias = free
    __shared__ float gtile[8][4][16][20];

    unsigned int* gcnt = flags + (size_t)g * 64 * FLAG_STRIDE_DW;

    f32x4 acc[4];
    const f32x4 fzero = {0.f, 0.f, 0.f, 0.f};

    // x-part for step tt: acc = x_tt @ Wx (this wave's K-slice)
    auto xpart = [&](int tt) {
        #pragma unroll
        for (int gg = 0; gg < 4; ++gg) acc[gg] = fzero;
        const float* xrow = x + ((size_t)(batch0 + m16) * SEQ + tt) * ISZ
                              + w * 64 + quad * 8;
        #pragma unroll
        for (int kk = 0; kk < 2; ++kk) {
            f32x4 x0 = *(const f32x4*)(xrow + kk * 32);
            f32x4 x1 = *(const f32x4*)(xrow + kk * 32 + 4);
            bf16x8 a;
            a[0] = f2bf(x0[0]); a[1] = f2bf(x0[1]);
            a[2] = f2bf(x0[2]); a[3] = f2bf(x0[3]);
            a[4] = f2bf(x1[0]); a[5] = f2bf(x1[1]);
            a[6] = f2bf(x1[2]); a[7] = f2bf(x1[3]);
            #pragma unroll
            for (int gg = 0; gg < 4; ++gg)
                acc[gg] = __builtin_amdgcn_mfma_f32_16x16x32_bf16(a, wx[gg][kk], acc[gg], 0, 0, 0);
        }
    };

    xpart(0);   // prologue: acc holds x-part of t=0

    for (int t = 0; t < SEQ; ++t) {
        // ---- wait: all 64 CUs of this group published step t-1 ----
        // 8 counters, each incremented by 8 CUs per step -> all == 8*t
        if (t && tid < 64) {
            const unsigned int target = 8u * (unsigned int)t;
            long long guard = 0;
            for (;;) {
                unsigned int v = 0xFFFFFFFFu;
                if (lane < 8)
                    v = __hip_atomic_load(gcnt + (size_t)lane * FLAG_STRIDE_DW,
                                          __ATOMIC_RELAXED, __HIP_MEMORY_SCOPE_AGENT);
                if (__all((int)(v >= target))) break;
                __builtin_amdgcn_s_sleep(1);
                if (++guard > (1LL << 22)) break;   // anti-hang safety valve
            }
        }
        __syncthreads();

        // ---- h part: acc += h_{t-1} @ Wh (distinct K-slice per wave) ----
        {
            const int rb = (t + 1) & 1;
            const unsigned short* hrow = hex + ((size_t)rb * BATCH + batch0 + m16) * HSZ
                                             + w * 128 + quad * 8;
            unsigned long long hp[4][2];
            #pragma unroll
            for (int kk = 0; kk < 4; ++kk) {
                hp[kk][0] = __hip_atomic_load((const unsigned long long*)(hrow + kk * 32),
                                              __ATOMIC_RELAXED, __HIP_MEMORY_SCOPE_AGENT);
                hp[kk][1] = __hip_atomic_load((const unsigned long long*)(hrow + kk * 32 + 4),
                                              __ATOMIC_RELAXED, __HIP_MEMORY_SCOPE_AGENT);
            }
            #pragma unroll
            for (int kk = 0; kk < 4; ++kk) {
                union { unsigned long long u[2]; bf16x8 v; } ha;
                ha.u[0] = hp[kk][0]; ha.u[1] = hp[kk][1];
                #pragma unroll
                for (int gg = 0; gg < 4; ++gg)
                    acc[gg] = __builtin_amdgcn_mfma_f32_16x16x32_bf16(ha.v, wh[gg][kk], acc[gg], 0, 0, 0);
            }
        }

        // ---- partials -> LDS (C/D layout: col = lane&15, row = quad*4 + r) ----
        #pragma unroll
        for (int gg = 0; gg < 4; ++gg)
            #pragma unroll
            for (int r = 0; r < 4; ++r)
                gtile[w][gg][quad * 4 + r][m16] = acc[gg][r];
        __syncthreads();

        // ---- elementwise gates + direct coherent publish ----
        if (tid < 256) {
            float gv[4];
            #pragma unroll
            for (int gg = 0; gg < 4; ++gg) {
                float s = bia[gg];
                #pragma unroll
                for (int ww = 0; ww < 8; ++ww) s += gtile[ww][gg][em][en];
                gv[gg] = s;
            }
            float f  = sigm(gv[0]);
            float i  = sigm(gv[1]);
            float ct = tanh_fast(gv[2]);
            float o  = sigm(gv[3]);
            c_state  = f * c_state + i * ct;
            float h_val = o * tanh_fast(c_state);

            // pair-pack via shfl, 4B coherent store from even-col lanes
            float hn = __shfl_xor(h_val, 1, 64);
            if ((en & 1) == 0) {
                unsigned int pk = (unsigned int)(unsigned short)f2bf(h_val)
                                | ((unsigned int)(unsigned short)f2bf(hn) << 16);
                __hip_atomic_store(
                    (unsigned int*)(hex + ((size_t)(t & 1) * BATCH + batch0 + em) * HSZ
                                        + q * 16 + en),
                    pk, __ATOMIC_RELAXED, __HIP_MEMORY_SCOPE_AGENT);
            }

            // off-critical-path output stores (drained by the same barrier)
            out[((size_t)(batch0 + em) * SEQ + t) * HSZ + q * 16 + en] = h_val;
            if (t == SEQ - 1) {
                size_t fin = (size_t)BATCH * SEQ * HSZ;
                out[fin + (size_t)(batch0 + em) * HSZ + q * 16 + en] = h_val;
                out[fin + (size_t)BATCH * HSZ + (size_t)(batch0 + em) * HSZ
                        + q * 16 + en] = c_state;
            }
            // drain coherent h stores in this wave before the barrier
            __asm__ volatile("s_waitcnt vmcnt(0)" ::: "memory");
        }
        __syncthreads();   // all publishing waves drained -> h_t globally visible

        // ---- arrival: one atomicAdd per CU (8 CUs share a counter line) ----
        if (tid == 0)
            __hip_atomic_fetch_add(gcnt + (size_t)(q >> 3) * FLAG_STRIDE_DW, 1u,
                                   __ATOMIC_RELAXED, __HIP_MEMORY_SCOPE_AGENT);

        // ---- x part for t+1: overlaps flag/data propagation to other CUs ----
        if (t + 1 < SEQ) xpart(t + 1);
    }
}

extern "C" void kernel_launch(void* const* d_in, const int* in_sizes, int n_in,
                              void* d_out, int out_size, void* d_ws, size_t ws_size,
                              hipStream_t stream) {
    const float* x    = (const float*)d_in[0];
    const float* W    = (const float*)d_in[1];
    const float* bias = (const float*)d_in[2];
    float* out        = (float*)d_out;

    unsigned short* hex   = (unsigned short*)d_ws;
    unsigned int*   flags = (unsigned int*)((char*)d_ws + HEX_BYTES);

    // zero h0 exchange buffers + arrival counters (ws re-poisoned each launch)
    hipMemsetAsync(d_ws, 0, HEX_BYTES + FLAG_BYTES, stream);

    lstm_persistent<<<256, 512, 0, stream>>>(x, W, bias, out, hex, flags);
}

// Round 4
// 2499.500 us; speedup vs baseline: 2.6218x; 1.0439x over previous
//
#include <hip/hip_runtime.h>
#include <hip/hip_bf16.h>

// SimpleLSTM on MI355X — round 7: epoch-in-data over PROVEN agent-scope atomics.
//   B=64, S=512, I=512, H=1024, gates = 4H = 4096
// R6 post-mortem: absmax 0.218 — local-mode (XCC consensus + sc0/plain-store
// L2 exchange) is the unproven piece; stale-tag spins tripped the guard and
// silently zeroed h (dead=1). The tagged-word math itself is layout-identical
// to R4's passing kernel.
// R7: revert coherence to R4's harness-proven primitive — 64-bit RELAXED
// AGENT-scope atomics for ALL exchange traffic; delete XCC/consensus/local/
// dead machinery entirely. Keep:
//   * EPOCH-IN-DATA: dword = bf16(h)<<16 | epoch(t+1). Consumers poll data
//     words directly -> ONE store->detect hop per step (R4 had 3: publish
//     drain, flag store, flag poll, then data load). Reuse safety: every block
//     reads all 1024 h-cols each step, so an epoch-t tag transitively proves
//     all step-(t-1) reads of the buffer being overwritten completed.
//   * 8 groups x 32 CUs x 8 batches (vs R4's 4x64x16): half the producers
//     awaited per step, half the h-bytes per CU.
//   * per-wave independent polls (wave proceeds when ITS 4 producers are
//     done); x-part GEMM pipelined after publish.

#define BATCH 64
#define SEQ   512
#define ISZ   512
#define HSZ   1024
#define G4    4096

#define NGRP  8
#define GB    8      // batches per group
#define SLOTS 32     // CUs per group

typedef short bf16x8 __attribute__((ext_vector_type(8)));
typedef float f32x4  __attribute__((ext_vector_type(4)));
typedef unsigned int u32x4 __attribute__((ext_vector_type(4)));

#define HEX_DW (NGRP * 2 * GB * HSZ)   // 131072 tagged dwords = 512 KB

static __device__ __forceinline__ short f2bf(float f) {
    __hip_bfloat16 h = __float2bfloat16(f);
    return *reinterpret_cast<short*>(&h);
}
static __device__ __forceinline__ float sigm(float x) {
    return 1.f / (1.f + __expf(-x));
}
static __device__ __forceinline__ float tanh_fast(float x) {
    x = fminf(15.f, fmaxf(-15.f, x));
    float e = __expf(2.f * x);
    return (e - 1.f) / (e + 1.f);
}

__global__ __launch_bounds__(512) void lstm_persistent(
    const float* __restrict__ x,     // [B][S][I] fp32
    const float* __restrict__ W,     // [I+H][4H] fp32
    const float* __restrict__ bias,  // [4H] fp32
    float* __restrict__ out,         // [B][S][H], then [B][H] h, [B][H] c
    unsigned int* hx)                // [NGRP][2][GB][HSZ] tagged words
{
    const int tid  = threadIdx.x;
    const int bid  = blockIdx.x;
    const int g    = bid & 7;           // group
    const int s    = bid >> 3;          // slot 0..31: owns h-cols [32s, 32s+32)
    const int w    = tid >> 6;          // wave 0..7 = h-K slice [128w, +128)
    const int lane = tid & 63;
    const int m16  = lane & 15;
    const int quad = lane >> 4;

    __shared__ short wxl[8][8][64][8];      // Wx kk=1 frags, 64 KB (self-wave read)
    __shared__ float gtile[8][8][8][16];    // 8 waves x 8 col-tiles x 8 rows, 32 KB

    // ---- preload weights as MFMA B-fragments ----
    // slot s: 8 col-tiles ct -> col = (ct>>1)*1024 + s*32 + (ct&1)*16
    // B-frag (16x16x32): lane holds B[k = quad*8 + j][n = lane&15]
    bf16x8 wh[8][4];
    bf16x8 wx0[8];
    #pragma unroll
    for (int ct = 0; ct < 8; ++ct) {
        const int col = (ct >> 1) * 1024 + s * 32 + (ct & 1) * 16 + m16;
        #pragma unroll
        for (int kk = 0; kk < 4; ++kk)
            #pragma unroll
            for (int j = 0; j < 8; ++j)
                wh[ct][kk][j] = f2bf(W[(size_t)(ISZ + w * 128 + kk * 32 + quad * 8 + j) * G4 + col]);
        bf16x8 t0, t1;
        #pragma unroll
        for (int j = 0; j < 8; ++j) {
            t0[j] = f2bf(W[(size_t)(w * 64 + quad * 8 + j) * G4 + col]);
            t1[j] = f2bf(W[(size_t)(w * 64 + 32 + quad * 8 + j) * G4 + col]);
        }
        wx0[ct] = t0;
        *(bf16x8*)&wxl[w][ct][lane][0] = t1;
    }

    // elementwise mapping (tid < 256): eb = batch-in-group, ec = h-col-in-32
    const int eb = tid >> 5;
    const int ec = tid & 31;
    float bia[4] = {0.f, 0.f, 0.f, 0.f};
    if (tid < 256) {
        #pragma unroll
        for (int gg2 = 0; gg2 < 4; ++gg2) bia[gg2] = bias[gg2 * 1024 + s * 32 + ec];
    }
    float c_state = 0.f;

    unsigned int* hxg = hx + (size_t)g * (2 * GB * HSZ);

    f32x4 acc[8];
    const f32x4 fzero = {0.f, 0.f, 0.f, 0.f};

    // x-part for step tt: acc = x_tt @ Wx (this wave's x-K slice [64w, +64))
    auto xpart = [&](int tt) {
        #pragma unroll
        for (int ct = 0; ct < 8; ++ct) acc[ct] = fzero;
        bf16x8 a0 = {0,0,0,0,0,0,0,0}, a1 = {0,0,0,0,0,0,0,0};
        if (m16 < 8) {
            const float* xr = x + ((size_t)(g * GB + m16) * SEQ + tt) * ISZ
                                + w * 64 + quad * 8;
            f32x4 p0 = *(const f32x4*)xr;
            f32x4 p1 = *(const f32x4*)(xr + 4);
            f32x4 p2 = *(const f32x4*)(xr + 32);
            f32x4 p3 = *(const f32x4*)(xr + 36);
            a0[0]=f2bf(p0[0]); a0[1]=f2bf(p0[1]); a0[2]=f2bf(p0[2]); a0[3]=f2bf(p0[3]);
            a0[4]=f2bf(p1[0]); a0[5]=f2bf(p1[1]); a0[6]=f2bf(p1[2]); a0[7]=f2bf(p1[3]);
            a1[0]=f2bf(p2[0]); a1[1]=f2bf(p2[1]); a1[2]=f2bf(p2[2]); a1[3]=f2bf(p2[3]);
            a1[4]=f2bf(p3[0]); a1[5]=f2bf(p3[1]); a1[6]=f2bf(p3[2]); a1[7]=f2bf(p3[3]);
        }
        #pragma unroll
        for (int ct = 0; ct < 8; ++ct)
            acc[ct] = __builtin_amdgcn_mfma_f32_16x16x32_bf16(a0, wx0[ct], acc[ct], 0, 0, 0);
        #pragma unroll
        for (int ct = 0; ct < 8; ++ct) {
            bf16x8 bx = *(const bf16x8*)&wxl[w][ct][lane][0];
            acc[ct] = __builtin_amdgcn_mfma_f32_16x16x32_bf16(a1, bx, acc[ct], 0, 0, 0);
        }
    };

    __syncthreads();   // wxl staged (same-wave reads, but keep it clean)
    xpart(0);

    for (int t = 0; t < SEQ; ++t) {
        // ---- poll + load h_{t-1}: tagged words, target epoch = t ----
        // (t=0 passes immediately: memset zeros == epoch 0 with h=0)
        const unsigned int tg = (unsigned int)t & 0xFFFFu;
        const int rb = (t + 1) & 1;
        u32x4 q[8];
        #pragma unroll
        for (int i = 0; i < 8; ++i) q[i] = (u32x4){0u, 0u, 0u, 0u};

        {
            const unsigned long long* hp64 = (const unsigned long long*)
                (hxg + ((size_t)rb * GB + m16) * HSZ + w * 128 + quad * 8);
            long long guard = 0;
            for (;;) {
                int ok = 1;
                if (m16 < 8) {
                    #pragma unroll
                    for (int kk = 0; kk < 4; ++kk) {
                        unsigned long long a0 = __hip_atomic_load(hp64 + kk * 16 + 0,
                            __ATOMIC_RELAXED, __HIP_MEMORY_SCOPE_AGENT);
                        unsigned long long a1 = __hip_atomic_load(hp64 + kk * 16 + 1,
                            __ATOMIC_RELAXED, __HIP_MEMORY_SCOPE_AGENT);
                        unsigned long long a2 = __hip_atomic_load(hp64 + kk * 16 + 2,
                            __ATOMIC_RELAXED, __HIP_MEMORY_SCOPE_AGENT);
                        unsigned long long a3 = __hip_atomic_load(hp64 + kk * 16 + 3,
                            __ATOMIC_RELAXED, __HIP_MEMORY_SCOPE_AGENT);
                        q[2*kk][0]   = (unsigned int)a0; q[2*kk][1]   = (unsigned int)(a0 >> 32);
                        q[2*kk][2]   = (unsigned int)a1; q[2*kk][3]   = (unsigned int)(a1 >> 32);
                        q[2*kk+1][0] = (unsigned int)a2; q[2*kk+1][1] = (unsigned int)(a2 >> 32);
                        q[2*kk+1][2] = (unsigned int)a3; q[2*kk+1][3] = (unsigned int)(a3 >> 32);
                    }
                    unsigned int bad = 0;
                    #pragma unroll
                    for (int i = 0; i < 8; ++i)
                        #pragma unroll
                        for (int j = 0; j < 4; ++j)
                            bad |= (q[i][j] ^ tg) & 0xFFFFu;
                    ok = (bad == 0);
                }
                if (__all(ok)) break;
                __builtin_amdgcn_s_sleep(1);
                if (++guard > (1LL << 22)) break;   // safety valve (never trips
            }                                       // with proven agent atomics)
        }

        // ---- h part: extract bf16 from tagged words, MFMA ----
        #pragma unroll
        for (int kk = 0; kk < 4; ++kk) {
            bf16x8 ha;
            #pragma unroll
            for (int j = 0; j < 4; ++j) {
                ha[j]     = (short)(q[2*kk][j] >> 16);
                ha[j + 4] = (short)(q[2*kk+1][j] >> 16);
            }
            #pragma unroll
            for (int ct = 0; ct < 8; ++ct)
                acc[ct] = __builtin_amdgcn_mfma_f32_16x16x32_bf16(ha, wh[ct][kk], acc[ct], 0, 0, 0);
        }

        // ---- partials -> LDS (C/D: col = lane&15, row = quad*4 + r; rows 0-7 real) ----
        if (quad < 2) {
            #pragma unroll
            for (int ct = 0; ct < 8; ++ct)
                #pragma unroll
                for (int r = 0; r < 4; ++r)
                    gtile[w][ct][quad * 4 + r][m16] = acc[ct][r];
        }
        __syncthreads();

        // ---- elementwise gates (registers only after this) ----
        float h_val = 0.f;
        unsigned int pword = 0;
        if (tid < 256) {
            float gv[4];
            #pragma unroll
            for (int gg2 = 0; gg2 < 4; ++gg2) {
                const int ct = gg2 * 2 + (ec >> 4);
                const int cn = ec & 15;
                float ss = bia[gg2];
                #pragma unroll
                for (int ww = 0; ww < 8; ++ww) ss += gtile[ww][ct][eb][cn];
                gv[gg2] = ss;
            }
            float f  = sigm(gv[0]);
            float i  = sigm(gv[1]);
            float cc = tanh_fast(gv[2]);
            float o  = sigm(gv[3]);
            c_state  = f * c_state + i * cc;
            h_val    = o * tanh_fast(c_state);
            pword = ((unsigned int)(unsigned short)f2bf(h_val) << 16)
                  | ((unsigned int)(t + 1) & 0xFFFFu);
        }
        __syncthreads();   // protects gtile reuse; cheap (no pending vmem deps)

        // ---- publish: 64-bit agent-scope store of two tagged words ----
        if (tid < 256) {
            unsigned int nw = __shfl_xor(pword, 1, 64);
            if (!(ec & 1)) {
                unsigned long long pk = (unsigned long long)pword
                                      | ((unsigned long long)nw << 32);
                __hip_atomic_store(
                    (unsigned long long*)(hxg + ((size_t)(t & 1) * GB + eb) * HSZ
                                              + s * 32 + ec),
                    pk, __ATOMIC_RELAXED, __HIP_MEMORY_SCOPE_AGENT);
            }
            // off-critical-path output stores
            out[((size_t)(g * GB + eb) * SEQ + t) * HSZ + s * 32 + ec] = h_val;
            if (t == SEQ - 1) {
                size_t fin = (size_t)BATCH * SEQ * HSZ;
                out[fin + (size_t)(g * GB + eb) * HSZ + s * 32 + ec] = h_val;
                out[fin + (size_t)BATCH * HSZ + (size_t)(g * GB + eb) * HSZ
                        + s * 32 + ec] = c_state;
            }
        }

        // ---- x part for t+1: overlaps publish propagation to other CUs ----
        if (t + 1 < SEQ) xpart(t + 1);
    }
}

extern "C" void kernel_launch(void* const* d_in, const int* in_sizes, int n_in,
                              void* d_out, int out_size, void* d_ws, size_t ws_size,
                              hipStream_t stream) {
    const float* x    = (const float*)d_in[0];
    const float* W    = (const float*)d_in[1];
    const float* bias = (const float*)d_in[2];
    float* out        = (float*)d_out;

    unsigned int* hx = (unsigned int*)d_ws;

    // zero tagged exchange: epoch 0 == valid h0 = 0
    hipMemsetAsync(d_ws, 0, HEX_DW * 4, stream);

    lstm_persistent<<<256, 512, 0, stream>>>(x, W, bias, out, hx);
}

// Round 5
// 2359.265 us; speedup vs baseline: 2.7776x; 1.0594x over previous
//
#include <hip/hip_runtime.h>
#include <hip/hip_bf16.h>

// SimpleLSTM on MI355X — round 8: kill the weight spills.
//   B=64, S=512, I=512, H=1024, gates = 4H = 4096
// R7 post-mortem: sync-topology changes (hops 3->1, group 64->32) gave only
// -4%. Counters show the real invariant: VGPR_Count=128 vs ~230 static demand
// -> ~100 VGPRs of persistent Wh/Wx fragments spilled to scratch (WRITE_SIZE
// excess ~84MB = one-time spill writes), RELOADED EVERY STEP inside the
// serial recurrence. That reload latency is the unexplained ~3us/step.
// R8:
//   * __launch_bounds__(512, 2): 96KB LDS already caps us at 1 block/CU
//     (2 waves/SIMD), so declare it -> 256-VGPR budget, weights stay resident.
//   * per-producer poll: each kk chunk (32 cols) == one producer's publish.
//     Spin on that chunk's tags -> extract -> MFMA immediately. Kills the
//     32-reg q[] array (peak pressure ~224) and overlaps early producers'
//     MFMA with polling for late ones.
//   * everything else identical to R7 (proven agent-scope atomics,
//     epoch-in-data, 8 groups x 32 CUs x 8 batches).

#define BATCH 64
#define SEQ   512
#define ISZ   512
#define HSZ   1024
#define G4    4096

#define NGRP  8
#define GB    8      // batches per group
#define SLOTS 32     // CUs per group

typedef short bf16x8 __attribute__((ext_vector_type(8)));
typedef float f32x4  __attribute__((ext_vector_type(4)));

#define HEX_DW (NGRP * 2 * GB * HSZ)   // 131072 tagged dwords = 512 KB

static __device__ __forceinline__ short f2bf(float f) {
    __hip_bfloat16 h = __float2bfloat16(f);
    return *reinterpret_cast<short*>(&h);
}
static __device__ __forceinline__ float sigm(float x) {
    return 1.f / (1.f + __expf(-x));
}
static __device__ __forceinline__ float tanh_fast(float x) {
    x = fminf(15.f, fmaxf(-15.f, x));
    float e = __expf(2.f * x);
    return (e - 1.f) / (e + 1.f);
}

__global__ __launch_bounds__(512, 2) void lstm_persistent(
    const float* __restrict__ x,     // [B][S][I] fp32
    const float* __restrict__ W,     // [I+H][4H] fp32
    const float* __restrict__ bias,  // [4H] fp32
    float* __restrict__ out,         // [B][S][H], then [B][H] h, [B][H] c
    unsigned int* __restrict__ hx)   // [NGRP][2][GB][HSZ] tagged words
{
    const int tid  = threadIdx.x;
    const int bid  = blockIdx.x;
    const int g    = bid & 7;           // group
    const int s    = bid >> 3;          // slot 0..31: owns h-cols [32s, 32s+32)
    const int w    = tid >> 6;          // wave 0..7 = h-K slice [128w, +128)
    const int lane = tid & 63;
    const int m16  = lane & 15;
    const int quad = lane >> 4;

    __shared__ short wxl[8][8][64][8];      // Wx kk=1 frags, 64 KB (self-wave read)
    __shared__ float gtile[8][8][8][16];    // 8 waves x 8 col-tiles x 8 rows, 32 KB

    // ---- preload weights as MFMA B-fragments ----
    // slot s: 8 col-tiles ct -> col = (ct>>1)*1024 + s*32 + (ct&1)*16
    // B-frag (16x16x32): lane holds B[k = quad*8 + j][n = lane&15]
    bf16x8 wh[8][4];
    bf16x8 wx0[8];
    #pragma unroll
    for (int ct = 0; ct < 8; ++ct) {
        const int col = (ct >> 1) * 1024 + s * 32 + (ct & 1) * 16 + m16;
        #pragma unroll
        for (int kk = 0; kk < 4; ++kk)
            #pragma unroll
            for (int j = 0; j < 8; ++j)
                wh[ct][kk][j] = f2bf(W[(size_t)(ISZ + w * 128 + kk * 32 + quad * 8 + j) * G4 + col]);
        bf16x8 t0, t1;
        #pragma unroll
        for (int j = 0; j < 8; ++j) {
            t0[j] = f2bf(W[(size_t)(w * 64 + quad * 8 + j) * G4 + col]);
            t1[j] = f2bf(W[(size_t)(w * 64 + 32 + quad * 8 + j) * G4 + col]);
        }
        wx0[ct] = t0;
        *(bf16x8*)&wxl[w][ct][lane][0] = t1;
    }

    // elementwise mapping (tid < 256): eb = batch-in-group, ec = h-col-in-32
    const int eb = tid >> 5;
    const int ec = tid & 31;
    float bia[4] = {0.f, 0.f, 0.f, 0.f};
    if (tid < 256) {
        #pragma unroll
        for (int gg2 = 0; gg2 < 4; ++gg2) bia[gg2] = bias[gg2 * 1024 + s * 32 + ec];
    }
    float c_state = 0.f;

    unsigned int* hxg = hx + (size_t)g * (2 * GB * HSZ);

    f32x4 acc[8];
    const f32x4 fzero = {0.f, 0.f, 0.f, 0.f};

    // x-part for step tt: acc = x_tt @ Wx (this wave's x-K slice [64w, +64))
    auto xpart = [&](int tt) {
        #pragma unroll
        for (int ct = 0; ct < 8; ++ct) acc[ct] = fzero;
        bf16x8 a0 = {0,0,0,0,0,0,0,0}, a1 = {0,0,0,0,0,0,0,0};
        if (m16 < 8) {
            const float* xr = x + ((size_t)(g * GB + m16) * SEQ + tt) * ISZ
                                + w * 64 + quad * 8;
            f32x4 p0 = *(const f32x4*)xr;
            f32x4 p1 = *(const f32x4*)(xr + 4);
            f32x4 p2 = *(const f32x4*)(xr + 32);
            f32x4 p3 = *(const f32x4*)(xr + 36);
            a0[0]=f2bf(p0[0]); a0[1]=f2bf(p0[1]); a0[2]=f2bf(p0[2]); a0[3]=f2bf(p0[3]);
            a0[4]=f2bf(p1[0]); a0[5]=f2bf(p1[1]); a0[6]=f2bf(p1[2]); a0[7]=f2bf(p1[3]);
            a1[0]=f2bf(p2[0]); a1[1]=f2bf(p2[1]); a1[2]=f2bf(p2[2]); a1[3]=f2bf(p2[3]);
            a1[4]=f2bf(p3[0]); a1[5]=f2bf(p3[1]); a1[6]=f2bf(p3[2]); a1[7]=f2bf(p3[3]);
        }
        #pragma unroll
        for (int ct = 0; ct < 8; ++ct)
            acc[ct] = __builtin_amdgcn_mfma_f32_16x16x32_bf16(a0, wx0[ct], acc[ct], 0, 0, 0);
        #pragma unroll
        for (int ct = 0; ct < 8; ++ct) {
            bf16x8 bx = *(const bf16x8*)&wxl[w][ct][lane][0];
            acc[ct] = __builtin_amdgcn_mfma_f32_16x16x32_bf16(a1, bx, acc[ct], 0, 0, 0);
        }
    };

    __syncthreads();   // wxl staged
    xpart(0);

    for (int t = 0; t < SEQ; ++t) {
        // ---- per-producer poll + h-MFMA: chunk kk == producer slot w*4+kk ----
        // tag target = t (t=0 passes immediately: memset zeros == epoch 0, h=0)
        const unsigned int tg = (unsigned int)t & 0xFFFFu;
        const int rb = (t + 1) & 1;
        const unsigned long long* hp64 = (const unsigned long long*)
            (hxg + ((size_t)rb * GB + m16) * HSZ + w * 128 + quad * 8);

        #pragma unroll
        for (int kk = 0; kk < 4; ++kk) {
            unsigned long long a0 = 0, a1 = 0, a2 = 0, a3 = 0;
            long long guard = 0;
            for (;;) {
                int ok = 1;
                if (m16 < 8) {
                    a0 = __hip_atomic_load(hp64 + kk * 16 + 0,
                        __ATOMIC_RELAXED, __HIP_MEMORY_SCOPE_AGENT);
                    a1 = __hip_atomic_load(hp64 + kk * 16 + 1,
                        __ATOMIC_RELAXED, __HIP_MEMORY_SCOPE_AGENT);
                    a2 = __hip_atomic_load(hp64 + kk * 16 + 2,
                        __ATOMIC_RELAXED, __HIP_MEMORY_SCOPE_AGENT);
                    a3 = __hip_atomic_load(hp64 + kk * 16 + 3,
                        __ATOMIC_RELAXED, __HIP_MEMORY_SCOPE_AGENT);
                    unsigned int bad = ((unsigned int)a0 ^ tg)
                                     | ((unsigned int)(a0 >> 32) ^ tg)
                                     | ((unsigned int)a1 ^ tg)
                                     | ((unsigned int)(a1 >> 32) ^ tg)
                                     | ((unsigned int)a2 ^ tg)
                                     | ((unsigned int)(a2 >> 32) ^ tg)
                                     | ((unsigned int)a3 ^ tg)
                                     | ((unsigned int)(a3 >> 32) ^ tg);
                    ok = ((bad & 0xFFFFu) == 0u);
                }
                if (__all(ok)) break;
                __builtin_amdgcn_s_sleep(1);
                if (++guard > (1LL << 22)) break;   // safety valve (never trips)
            }
            bf16x8 ha;
            ha[0] = (short)((unsigned int)a0 >> 16);
            ha[1] = (short)(a0 >> 48);
            ha[2] = (short)((unsigned int)a1 >> 16);
            ha[3] = (short)(a1 >> 48);
            ha[4] = (short)((unsigned int)a2 >> 16);
            ha[5] = (short)(a2 >> 48);
            ha[6] = (short)((unsigned int)a3 >> 16);
            ha[7] = (short)(a3 >> 48);
            #pragma unroll
            for (int ct = 0; ct < 8; ++ct)
                acc[ct] = __builtin_amdgcn_mfma_f32_16x16x32_bf16(ha, wh[ct][kk], acc[ct], 0, 0, 0);
        }

        // ---- partials -> LDS (C/D: col = lane&15, row = quad*4 + r; rows 0-7 real) ----
        if (quad < 2) {
            #pragma unroll
            for (int ct = 0; ct < 8; ++ct)
                #pragma unroll
                for (int r = 0; r < 4; ++r)
                    gtile[w][ct][quad * 4 + r][m16] = acc[ct][r];
        }
        __syncthreads();

        // ---- elementwise gates (registers only after this) ----
        float h_val = 0.f;
        unsigned int pword = 0;
        if (tid < 256) {
            float gv[4];
            #pragma unroll
            for (int gg2 = 0; gg2 < 4; ++gg2) {
                const int ct = gg2 * 2 + (ec >> 4);
                const int cn = ec & 15;
                float ss = bia[gg2];
                #pragma unroll
                for (int ww = 0; ww < 8; ++ww) ss += gtile[ww][ct][eb][cn];
                gv[gg2] = ss;
            }
            float f  = sigm(gv[0]);
            float i  = sigm(gv[1]);
            float cc = tanh_fast(gv[2]);
            float o  = sigm(gv[3]);
            c_state  = f * c_state + i * cc;
            h_val    = o * tanh_fast(c_state);
            pword = ((unsigned int)(unsigned short)f2bf(h_val) << 16)
                  | ((unsigned int)(t + 1) & 0xFFFFu);
        }
        __syncthreads();   // protects gtile reuse; cheap (no pending vmem deps)

        // ---- publish: 64-bit agent-scope store of two tagged words ----
        if (tid < 256) {
            unsigned int nw = __shfl_xor(pword, 1, 64);
            if (!(ec & 1)) {
                unsigned long long pk = (unsigned long long)pword
                                      | ((unsigned long long)nw << 32);
                __hip_atomic_store(
                    (unsigned long long*)(hxg + ((size_t)(t & 1) * GB + eb) * HSZ
                                              + s * 32 + ec),
                    pk, __ATOMIC_RELAXED, __HIP_MEMORY_SCOPE_AGENT);
            }
            // off-critical-path output stores
            out[((size_t)(g * GB + eb) * SEQ + t) * HSZ + s * 32 + ec] = h_val;
            if (t == SEQ - 1) {
                size_t fin = (size_t)BATCH * SEQ * HSZ;
                out[fin + (size_t)(g * GB + eb) * HSZ + s * 32 + ec] = h_val;
                out[fin + (size_t)BATCH * HSZ + (size_t)(g * GB + eb) * HSZ
                        + s * 32 + ec] = c_state;
            }
        }

        // ---- x part for t+1: overlaps publish propagation to other CUs ----
        if (t + 1 < SEQ) xpart(t + 1);
    }
}

extern "C" void kernel_launch(void* const* d_in, const int* in_sizes, int n_in,
                              void* d_out, int out_size, void* d_ws, size_t ws_size,
                              hipStream_t stream) {
    const float* x    = (const float*)d_in[0];
    const float* W    = (const float*)d_in[1];
    const float* bias = (const float*)d_in[2];
    float* out        = (float*)d_out;

    unsigned int* hx = (unsigned int*)d_ws;

    // zero tagged exchange: epoch 0 == valid h0 = 0
    hipMemsetAsync(d_ws, 0, HEX_DW * 4, stream);

    lstm_persistent<<<256, 512, 0, stream>>>(x, W, bias, out, hx);
}